// Round 1
// baseline (390.160 us; speedup 1.0000x reference)
//
#include <hip/hip_runtime.h>
#include <math.h>

// MuLUT ConvBlock: 6 branches x 8 images (4 rotations x batch 2) x 64x64 px.
// Per pixel: conv3x3(2ch->64) -> 4x dense(concat to 320) -> 8ch head ->
// pixel-shuffle x2 -> round(tanh*127) -> inverse-rotate -> sum/2.
//
// Block = (branch b, image n, row). 256 threads, act tile [320][64] f32 in LDS
// (80KB -> 2 blocks/CU). Thread computes 4ch x 4px per dense stage.
// Epilogue: exact-integer f32 atomicAdd into out (values are integers*0.5).

__global__ __launch_bounds__(256, 2) void mulut_branch_kernel(
    const float* __restrict__ x,  const float* __restrict__ px_,
    const float* __restrict__ W1, const float* __restrict__ B1,
    const float* __restrict__ W2, const float* __restrict__ B2,
    const float* __restrict__ W3, const float* __restrict__ B3,
    const float* __restrict__ W4, const float* __restrict__ B4,
    const float* __restrict__ W5, const float* __restrict__ B5,
    const float* __restrict__ W6, const float* __restrict__ B6,
    float* __restrict__ out)
{
    __shared__ float actL[320][64];   // 81920 B

    const int blk   = blockIdx.x;     // b*512 + n*64 + row
    const int row   = blk & 63;
    const int n     = (blk >> 6) & 7; // n = r*2 + batch
    const int b     = blk >> 9;       // 0..5
    const int c     = (b >= 3) ? 1 : 0;
    const int r     = n >> 1;
    const int batch = n & 1;

    const int tid = threadIdx.x;
    const int cg  = tid >> 4;         // 0..15
    const int pg  = tid & 15;         // 0..15
    const int ch0 = cg << 2;
    const int px0 = pg << 2;

    // ---------------- conv 3x3 VALID on rotated + edge-padded image ----------
    {
        float acc[4][4];
        #pragma unroll
        for (int o = 0; o < 4; ++o) {
            const float bv = B1[b*64 + ch0 + o];
            #pragma unroll
            for (int p = 0; p < 4; ++p) acc[o][p] = bv;
        }
        const float* img0 = x   + ((batch*2 + c) << 12);  // [64][64]
        const float* img1 = px_ + ((batch*2 + c) << 12);
        #pragma unroll
        for (int ci2 = 0; ci2 < 2; ++ci2) {
            const float* img = (ci2 == 0) ? img0 : img1;
            #pragma unroll
            for (int di = 0; di < 3; ++di) {
                const int ii = min(row + di, 63);
                float rg[6];
                #pragma unroll
                for (int u = 0; u < 6; ++u) {
                    const int jj = min(px0 + u, 63);
                    int si, sj;
                    if (r == 0)      { si = ii;       sj = jj;      }
                    else if (r == 1) { si = jj;       sj = 63 - ii; }
                    else if (r == 2) { si = 63 - ii;  sj = 63 - jj; }
                    else             { si = 63 - jj;  sj = ii;      }
                    rg[u] = img[si*64 + sj];
                }
                #pragma unroll
                for (int dj = 0; dj < 3; ++dj) {
                    #pragma unroll
                    for (int o = 0; o < 4; ++o) {
                        const float w = W1[((b*64 + ch0 + o)*2 + ci2)*9 + di*3 + dj];
                        #pragma unroll
                        for (int p = 0; p < 4; ++p)
                            acc[o][p] = fmaf(rg[dj + p], w, acc[o][p]);
                    }
                }
            }
        }
        #pragma unroll
        for (int o = 0; o < 4; ++o)
            #pragma unroll
            for (int p = 0; p < 4; ++p)
                actL[ch0 + o][px0 + p] = fmaxf(acc[o][p], 0.f);
    }
    __syncthreads();

    // ---------------- dense stages: K = 64,128,192,256; N = 64 ---------------
    const float* Wst[4] = { W2 + (size_t)b*64*64,  W3 + (size_t)b*64*128,
                            W4 + (size_t)b*64*192, W5 + (size_t)b*64*256 };
    const float* Bst[4] = { B2 + b*64, B3 + b*64, B4 + b*64, B5 + b*64 };

    for (int s = 0; s < 4; ++s) {
        const int K = 64 * (s + 1);
        const float* Wg = Wst[s] + (size_t)ch0 * K;   // row-major [64][K]
        float acc[4][4];
        #pragma unroll
        for (int o = 0; o < 4; ++o) {
            const float bv = Bst[s][ch0 + o];
            #pragma unroll
            for (int p = 0; p < 4; ++p) acc[o][p] = bv;
        }
        for (int k = 0; k < K; k += 4) {
            float a_[4][4];
            #pragma unroll
            for (int u = 0; u < 4; ++u) {
                const float4 av = *(const float4*)&actL[k + u][px0];
                a_[u][0] = av.x; a_[u][1] = av.y; a_[u][2] = av.z; a_[u][3] = av.w;
            }
            #pragma unroll
            for (int o = 0; o < 4; ++o) {
                const float4 wv = *(const float4*)&Wg[o*K + k];
                #pragma unroll
                for (int p = 0; p < 4; ++p) {
                    acc[o][p] = fmaf(wv.x, a_[0][p], acc[o][p]);
                    acc[o][p] = fmaf(wv.y, a_[1][p], acc[o][p]);
                    acc[o][p] = fmaf(wv.z, a_[2][p], acc[o][p]);
                    acc[o][p] = fmaf(wv.w, a_[3][p], acc[o][p]);
                }
            }
        }
        #pragma unroll
        for (int o = 0; o < 4; ++o)
            #pragma unroll
            for (int p = 0; p < 4; ++p)
                actL[K + ch0 + o][px0 + p] = fmaxf(acc[o][p], 0.f);
        __syncthreads();
    }

    // ---------------- head: 8 ch x K=320, fused epilogue ----------------------
    {
        const int ch  = tid >> 5;         // 0..7
        const int qx0 = (tid & 31) * 2;   // 0,2,..,62
        const float* Wg = W6 + ((size_t)b*8 + ch)*320;
        float acc0 = B6[b*8 + ch];
        float acc1 = acc0;
        for (int k = 0; k < 320; k += 4) {
            const float4 wv = *(const float4*)&Wg[k];
            acc0 = fmaf(wv.x, actL[k  ][qx0  ], acc0);
            acc1 = fmaf(wv.x, actL[k  ][qx0+1], acc1);
            acc0 = fmaf(wv.y, actL[k+1][qx0  ], acc0);
            acc1 = fmaf(wv.y, actL[k+1][qx0+1], acc1);
            acc0 = fmaf(wv.z, actL[k+2][qx0  ], acc0);
            acc1 = fmaf(wv.z, actL[k+2][qx0+1], acc1);
            acc0 = fmaf(wv.w, actL[k+3][qx0  ], acc0);
            acc1 = fmaf(wv.w, actL[k+3][qx0+1], acc1);
        }
        // pixel-shuffle + inverse rotation + round(tanh*127), sum/2 via atomics
        const int oc = ch >> 2;
        const int a  = (ch >> 1) & 1;
        const int bb = ch & 1;
        const int ip = 2*row + a;
        #pragma unroll
        for (int p = 0; p < 2; ++p) {
            const int jp = 2*(qx0 + p) + bb;
            int I, J;
            if (r == 0)      { I = ip;        J = jp;       }
            else if (r == 1) { I = jp;        J = 127 - ip; }
            else if (r == 2) { I = 127 - ip;  J = 127 - jp; }
            else             { I = 127 - jp;  J = ip;       }
            const float z = (p == 0) ? acc0 : acc1;
            const float v = rintf(tanhf(z) * 127.0f);
            atomicAdd(out + (((batch*2 + oc) << 14) + I*128 + J), v * 0.5f);
        }
    }
}

extern "C" void kernel_launch(void* const* d_in, const int* in_sizes, int n_in,
                              void* d_out, int out_size, void* d_ws, size_t ws_size,
                              hipStream_t stream) {
    const float* x   = (const float*)d_in[0];
    const float* pxv = (const float*)d_in[1];
    const float* W1  = (const float*)d_in[2];
    const float* B1  = (const float*)d_in[3];
    const float* W2  = (const float*)d_in[4];
    const float* B2  = (const float*)d_in[5];
    const float* W3  = (const float*)d_in[6];
    const float* B3  = (const float*)d_in[7];
    const float* W4  = (const float*)d_in[8];
    const float* B4  = (const float*)d_in[9];
    const float* W5  = (const float*)d_in[10];
    const float* B5  = (const float*)d_in[11];
    const float* W6  = (const float*)d_in[12];
    const float* B6  = (const float*)d_in[13];
    float* out = (float*)d_out;

    hipMemsetAsync(out, 0, (size_t)out_size * sizeof(float), stream);
    mulut_branch_kernel<<<dim3(6*8*64), dim3(256), 0, stream>>>(
        x, pxv, W1, B1, W2, B2, W3, B3, W4, B4, W5, B5, W6, B6, out);
}

// Round 3
// 363.705 us; speedup vs baseline: 1.0727x; 1.0727x over previous
//
#include <hip/hip_runtime.h>
#include <math.h>

// MuLUT ConvBlock on MFMA. 6 branches x 8 images x 64x64 px.
// conv3x3 (fp32 VALU) -> 4 dense stages + head via mfma_f32_16x16x32_bf16
// with hi/lo bf16 split (3 MFMAs per k-step, ~fp32 accuracy).
// Activations: LDS [px][ch] bf16 hi/lo planes, XOR block-swizzled.
// Weights: prep kernel -> fragment-major hi/lo planes in d_ws (coalesced A-loads).

typedef short bf16x8  __attribute__((ext_vector_type(8)));
typedef short short4v __attribute__((ext_vector_type(4)));
typedef float f32x4   __attribute__((ext_vector_type(4)));

__device__ __forceinline__ short f2bf_bits(float v) {
    union { float f; unsigned u; } x; x.f = v;
    unsigned r = x.u + 0x7FFFu + ((x.u >> 16) & 1u);   // RNE
    return (short)(r >> 16);
}
__device__ __forceinline__ float bf2f(short s) {
    union { unsigned u; float f; } x; x.u = ((unsigned)(unsigned short)s) << 16;
    return x.f;
}

// ---------------- weight prep: fp32 -> frag-major bf16 hi/lo planes ----------
// frag layout: elem(frag, lane, j) = W[m*16 + (lane&15)][kb*32 + (lane>>4)*8 + j]
// frags: W2:0..47  W3:48..143  W4:144..287  W5:288..479  W6(pad16):480..539
__global__ void prep_weights(const float* __restrict__ W2, const float* __restrict__ W3,
                             const float* __restrict__ W4, const float* __restrict__ W5,
                             const float* __restrict__ W6,
                             short* __restrict__ whi, short* __restrict__ wlo)
{
    const int t    = blockIdx.x * 256 + threadIdx.x;   // 0..34559
    const int frag = t >> 6;
    const int lane = t & 63;
    const int row  = lane & 15;
    const int kq   = lane >> 4;

    const float* src; int b, m, kb, K;
    if (frag < 48)       { int f = frag;       b = f / 8;  int r = f % 8;  m = r / 2; kb = r % 2; K = 64;  src = W2; }
    else if (frag < 144) { int f = frag - 48;  b = f / 16; int r = f % 16; m = r / 4; kb = r % 4; K = 128; src = W3; }
    else if (frag < 288) { int f = frag - 144; b = f / 24; int r = f % 24; m = r / 6; kb = r % 6; K = 192; src = W4; }
    else if (frag < 480) { int f = frag - 288; b = f / 32; int r = f % 32; m = r / 8; kb = r % 8; K = 256; src = W5; }
    else                 { int f = frag - 480; b = f / 10; kb = f % 10;    m = 0;     K = 320; src = W6; }

    const size_t dbase = ((size_t)frag << 9) + ((size_t)lane << 3);
    #pragma unroll
    for (int j = 0; j < 8; ++j) {
        const int k = kb * 32 + kq * 8 + j;
        float v;
        if (frag < 480) {
            const int o = m * 16 + row;
            v = src[((size_t)b * 64 + o) * K + k];
        } else {
            v = (row < 8) ? src[((size_t)b * 8 + row) * 320 + k] : 0.0f;
        }
        const short h = f2bf_bits(v);
        whi[dbase + j] = h;
        wlo[dbase + j] = f2bf_bits(v - bf2f(h));
    }
}

// ---------------- main kernel ------------------------------------------------
__global__ __launch_bounds__(256, 2) void mulut_mfma_kernel(
    const float* __restrict__ x,  const float* __restrict__ px_,
    const float* __restrict__ W1, const float* __restrict__ B1,
    const float* __restrict__ B2, const float* __restrict__ B3,
    const float* __restrict__ B4, const float* __restrict__ B5,
    const float* __restrict__ B6,
    const short* __restrict__ whi, const short* __restrict__ wlo,
    float* __restrict__ out)
{
    __shared__ __align__(16) short act_hi[64 * 320];   // [px][ch] swizzled, 40KB
    __shared__ __align__(16) short act_lo[64 * 320];   // 40KB

    const int blk   = blockIdx.x;     // b*512 + n*64 + row
    const int row   = blk & 63;
    const int n     = (blk >> 6) & 7;
    const int b     = blk >> 9;
    const int c     = (b >= 3) ? 1 : 0;
    const int r     = n >> 1;
    const int batch = n & 1;

    const int tid  = threadIdx.x;
    const int wave = tid >> 6;
    const int lane = tid & 63;
    const int lrow = lane & 15;       // A-row offset / B-col (px) offset
    const int lkq  = lane >> 4;       // k-quad / C row-quad

    // ---------------- conv 3x3 (fp32 VALU, exact), write bf16 hi/lo tile -----
    {
        const int cg  = tid >> 4;
        const int pg  = tid & 15;
        const int ch0 = cg << 2;
        const int px0 = pg << 2;

        float acc[4][4];
        #pragma unroll
        for (int o = 0; o < 4; ++o) {
            const float bv = B1[b * 64 + ch0 + o];
            #pragma unroll
            for (int p = 0; p < 4; ++p) acc[o][p] = bv;
        }
        const float* img0 = x   + ((batch * 2 + c) << 12);
        const float* img1 = px_ + ((batch * 2 + c) << 12);
        #pragma unroll
        for (int ci2 = 0; ci2 < 2; ++ci2) {
            const float* img = (ci2 == 0) ? img0 : img1;
            #pragma unroll
            for (int di = 0; di < 3; ++di) {
                const int ii = min(row + di, 63);
                float rg[6];
                #pragma unroll
                for (int u = 0; u < 6; ++u) {
                    const int jj = min(px0 + u, 63);
                    int si, sj;
                    if (r == 0)      { si = ii;       sj = jj;      }
                    else if (r == 1) { si = jj;       sj = 63 - ii; }
                    else if (r == 2) { si = 63 - ii;  sj = 63 - jj; }
                    else             { si = 63 - jj;  sj = ii;      }
                    rg[u] = img[si * 64 + sj];
                }
                #pragma unroll
                for (int dj = 0; dj < 3; ++dj) {
                    #pragma unroll
                    for (int o = 0; o < 4; ++o) {
                        const float w = W1[((b * 64 + ch0 + o) * 2 + ci2) * 9 + di * 3 + dj];
                        #pragma unroll
                        for (int p = 0; p < 4; ++p)
                            acc[o][p] = fmaf(rg[dj + p], w, acc[o][p]);
                    }
                }
            }
        }
        // transposed swizzled store: 4 ch quad per px, hi/lo planes
        const int blk8 = ch0 >> 3;
        #pragma unroll
        for (int p = 0; p < 4; ++p) {
            const int px = px0 + p;
            short4v qh, ql;
            #pragma unroll
            for (int o = 0; o < 4; ++o) {
                const float v = fmaxf(acc[o][p], 0.0f);
                const short h = f2bf_bits(v);
                qh[o] = h;
                ql[o] = f2bf_bits(v - bf2f(h));
            }
            const int sw  = (blk8 & ~7) | ((blk8 ^ px) & 7);
            const int idx = px * 320 + sw * 8 + (ch0 & 7);
            *(short4v*)&act_hi[idx] = qh;
            *(short4v*)&act_lo[idx] = ql;
        }
    }
    __syncthreads();

    // ---------------- dense stages on MFMA (wave-local px-tile) --------------
    const int px0w = wave * 16;
    const int pxl  = px0w + lrow;                 // this lane's px (B-col)
    const float* Bs[4] = { B2 + b * 64, B3 + b * 64, B4 + b * 64, B5 + b * 64 };
    const int   Fbase[4] = { 0, 48, 144, 288 };

    #pragma unroll
    for (int s = 0; s < 4; ++s) {
        const int K  = 64 * (s + 1);
        const int KB = K >> 5;
        f32x4 acc[4];
        #pragma unroll
        for (int m = 0; m < 4; ++m) {
            #pragma unroll
            for (int rr = 0; rr < 4; ++rr)
                acc[m][rr] = Bs[s][m * 16 + lkq * 4 + rr];
        }
        for (int kb = 0; kb < KB; ++kb) {
            const int k0   = kb * 32 + lkq * 8;
            const int kblk = k0 >> 3;
            const int sw   = (kblk & ~7) | ((kblk ^ pxl) & 7);
            const int idx  = pxl * 320 + sw * 8;
            const bf16x8 bhi = *(const bf16x8*)&act_hi[idx];
            const bf16x8 blo = *(const bf16x8*)&act_lo[idx];
            #pragma unroll
            for (int m = 0; m < 4; ++m) {
                const size_t fo = ((size_t)(Fbase[s] + (b * 4 + m) * KB + kb) << 9) + (lane << 3);
                const bf16x8 ahi = *(const bf16x8*)(whi + fo);
                const bf16x8 alo = *(const bf16x8*)(wlo + fo);
                acc[m] = __builtin_amdgcn_mfma_f32_16x16x32_bf16(ahi, bhi, acc[m], 0, 0, 0);
                acc[m] = __builtin_amdgcn_mfma_f32_16x16x32_bf16(ahi, blo, acc[m], 0, 0, 0);
                acc[m] = __builtin_amdgcn_mfma_f32_16x16x32_bf16(alo, bhi, acc[m], 0, 0, 0);
            }
        }
        // ReLU + hi/lo store (wave-local px, no barrier needed)
        #pragma unroll
        for (int m = 0; m < 4; ++m) {
            const int chq  = K + m * 16 + lkq * 4;     // output ch quad base
            short4v qh, ql;
            #pragma unroll
            for (int rr = 0; rr < 4; ++rr) {
                const float v = fmaxf(acc[m][rr], 0.0f);
                const short h = f2bf_bits(v);
                qh[rr] = h;
                ql[rr] = f2bf_bits(v - bf2f(h));
            }
            const int blk8 = chq >> 3;
            const int sw   = (blk8 & ~7) | ((blk8 ^ pxl) & 7);
            const int idx  = pxl * 320 + sw * 8 + (chq & 7);
            *(short4v*)&act_hi[idx] = qh;
            *(short4v*)&act_lo[idx] = ql;
        }
    }

    // ---------------- head (M=16 padded, K=320) + fused epilogue -------------
    {
        f32x4 hacc;
        #pragma unroll
        for (int rr = 0; rr < 4; ++rr) {
            const int ch = lkq * 4 + rr;
            hacc[rr] = (ch < 8) ? B6[b * 8 + ch] : 0.0f;
        }
        for (int kb = 0; kb < 10; ++kb) {
            const int k0   = kb * 32 + lkq * 8;
            const int kblk = k0 >> 3;
            const int sw   = (kblk & ~7) | ((kblk ^ pxl) & 7);
            const int idx  = pxl * 320 + sw * 8;
            const bf16x8 bhi = *(const bf16x8*)&act_hi[idx];
            const bf16x8 blo = *(const bf16x8*)&act_lo[idx];
            const size_t fo = ((size_t)(480 + b * 10 + kb) << 9) + (lane << 3);
            const bf16x8 ahi = *(const bf16x8*)(whi + fo);
            const bf16x8 alo = *(const bf16x8*)(wlo + fo);
            hacc = __builtin_amdgcn_mfma_f32_16x16x32_bf16(ahi, bhi, hacc, 0, 0, 0);
            hacc = __builtin_amdgcn_mfma_f32_16x16x32_bf16(ahi, blo, hacc, 0, 0, 0);
            hacc = __builtin_amdgcn_mfma_f32_16x16x32_bf16(alo, bhi, hacc, 0, 0, 0);
        }
        // pixel-shuffle + inverse rotation + round(tanh*127) + sum/2
        #pragma unroll
        for (int rr = 0; rr < 4; ++rr) {
            const int ch = lkq * 4 + rr;
            if (ch < 8) {
                const int oc = ch >> 2;
                const int a  = (ch >> 1) & 1;
                const int bb = ch & 1;
                const int ip = 2 * row + a;
                const int jp = 2 * pxl + bb;
                int I, J;
                if (r == 0)      { I = ip;        J = jp;       }
                else if (r == 1) { I = jp;        J = 127 - ip; }
                else if (r == 2) { I = 127 - ip;  J = 127 - jp; }
                else             { I = 127 - jp;  J = ip;       }
                const float v = rintf(tanhf(hacc[rr]) * 127.0f);
                atomicAdd(out + (((batch * 2 + oc) << 14) + I * 128 + J), v * 0.5f);
            }
        }
    }
}

extern "C" void kernel_launch(void* const* d_in, const int* in_sizes, int n_in,
                              void* d_out, int out_size, void* d_ws, size_t ws_size,
                              hipStream_t stream) {
    const float* x   = (const float*)d_in[0];
    const float* pxv = (const float*)d_in[1];
    const float* W1  = (const float*)d_in[2];
    const float* B1  = (const float*)d_in[3];
    const float* W2  = (const float*)d_in[4];
    const float* B2  = (const float*)d_in[5];
    const float* W3  = (const float*)d_in[6];
    const float* B3  = (const float*)d_in[7];
    const float* W4  = (const float*)d_in[8];
    const float* B4  = (const float*)d_in[9];
    const float* W5  = (const float*)d_in[10];
    const float* B5  = (const float*)d_in[11];
    const float* W6  = (const float*)d_in[12];
    const float* B6  = (const float*)d_in[13];
    float* out = (float*)d_out;

    short* whi = (short*)d_ws;                 // 276480 bf16 bit-patterns
    short* wlo = whi + 276480;

    hipMemsetAsync(out, 0, (size_t)out_size * sizeof(float), stream);
    prep_weights<<<dim3(135), dim3(256), 0, stream>>>(W2, W3, W4, W5, W6, whi, wlo);
    mulut_mfma_kernel<<<dim3(6 * 8 * 64), dim3(256), 0, stream>>>(
        x, pxv, W1, B1, B2, B3, B4, B5, B6, whi, wlo, out);
}

// Round 6
// 184.667 us; speedup vs baseline: 2.1128x; 1.9695x over previous
//
#include <hip/hip_runtime.h>
#include <math.h>

// MuLUT ConvBlock, round 4: weights staged once per block into 160KB LDS
// (counted-vmcnt pipeline), activations kept entirely in VGPRs via a
// permuted-K fragment convention (MFMA C-quad == next stage's B-frag).
// 768 blocks x 512 threads; wave = 2x16px tiles; hi/lo bf16 split (3 MFMA/k).

typedef short bf16x8 __attribute__((ext_vector_type(8)));
typedef float f32x4  __attribute__((ext_vector_type(4)));

__device__ __forceinline__ short f2bf_bits(float v) {
    union { float f; unsigned u; } x; x.f = v;
    unsigned r = x.u + 0x7FFFu + ((x.u >> 16) & 1u);   // RNE
    return (short)(r >> 16);
}
__device__ __forceinline__ float bf2f(short s) {
    union { unsigned u; float f; } x; x.u = ((unsigned)(unsigned short)s) << 16;
    return x.f;
}

// ---------------------------------------------------------------------------
// prep: weights -> per-branch contiguous fragment image in d_ws.
// Branch block = 90 slots x 2KB (hi 1KB | lo 1KB). slot = SlotOff[s]+kb*4+m,
// SlotOff = {0,8,24,48}, head slots 80..89.
// Fragment element (lane,j): out = m*16 + (lane&15),
//   k_in = kb*32 + (j&4 ? 16 : 0) + (lane>>4)*4 + (j&3)   [permuted-K]
// Plus W1 repack: w1p[(b*4+kq)*288 + (img*9+tap)*16 + s16*4 + t].
// ---------------------------------------------------------------------------
__global__ void prep_weights(const float* __restrict__ W1, const float* __restrict__ W2,
                             const float* __restrict__ W3, const float* __restrict__ W4,
                             const float* __restrict__ W5, const float* __restrict__ W6,
                             short* __restrict__ wsw, float* __restrict__ w1p)
{
    if (blockIdx.x < 135) {
        const int t = blockIdx.x * 256 + threadIdx.x;   // 0..34559
        const int frag = t >> 6, lane = t & 63;
        const int b = frag / 90, slot = frag % 90;
        const int kqh = lane >> 4, rowl = lane & 15;
        const float* src; int K, kb, m; bool head = false;
        if (slot < 8)       { src = W2; K = 64;  kb = slot >> 2;        m = slot & 3; }
        else if (slot < 24) { src = W3; K = 128; kb = (slot - 8) >> 2;  m = slot & 3; }
        else if (slot < 48) { src = W4; K = 192; kb = (slot - 24) >> 2; m = slot & 3; }
        else if (slot < 80) { src = W5; K = 256; kb = (slot - 48) >> 2; m = slot & 3; }
        else                { src = W6; K = 320; kb = slot - 80; m = 0; head = true; }
        short* hi = wsw + (size_t)b * 92160 + slot * 1024 + (lane << 3);
        short* lo = hi + 512;
        #pragma unroll
        for (int j = 0; j < 8; ++j) {
            const int k = kb * 32 + ((j & 4) ? 16 : 0) + kqh * 4 + (j & 3);
            float v;
            if (!head) v = src[(size_t)(b * 64 + m * 16 + rowl) * K + k];
            else       v = (rowl < 8) ? src[(size_t)(b * 8 + rowl) * 320 + k] : 0.0f;
            const short h = f2bf_bits(v);
            hi[j] = h;
            lo[j] = f2bf_bits(v - bf2f(h));
        }
    } else {
        for (int d = threadIdx.x; d < 6912; d += 256) {
            const int bq = d / 288, rem = d % 288;
            const int it2 = rem >> 4, s16 = (rem >> 2) & 3, tt = rem & 3;
            const int b = bq >> 2, kq = bq & 3;
            const int img = it2 / 9, tap = it2 % 9;
            w1p[d] = W1[(size_t)((b * 64 + s16 * 16 + kq * 4 + tt) * 2 + img) * 9 + tap];
        }
    }
}

// ---------------------------------------------------------------------------
__device__ __forceinline__ void pack_kb(const f32x4 a, const f32x4 bq,
                                        bf16x8* ph, bf16x8* pl) {
    bf16x8 h, l;
    #pragma unroll
    for (int e = 0; e < 4; ++e) {
        float v = fmaxf(a[e], 0.0f);
        short hs = f2bf_bits(v);
        h[e] = hs; l[e] = f2bf_bits(v - bf2f(hs));
        float v2 = fmaxf(bq[e], 0.0f);
        short hs2 = f2bf_bits(v2);
        h[4 + e] = hs2; l[4 + e] = f2bf_bits(v2 - bf2f(hs2));
    }
    *ph = h; *pl = l;
}

#define ASM_VMCNT(N) asm volatile("s_waitcnt vmcnt(" #N ")" ::: "memory")

#define DENSE_STAGE(KB_IN, SLOT0, BIAS, OUTKB)                                          \
  {                                                                                      \
    f32x4 sacc[2][4];                                                                    \
    _Pragma("unroll") for (int p = 0; p < 2; ++p)                                        \
      _Pragma("unroll") for (int m = 0; m < 4; ++m)                                      \
        _Pragma("unroll") for (int rr = 0; rr < 4; ++rr)                                 \
          sacc[p][m][rr] = BIAS[m * 4 + rr];                                             \
    _Pragma("unroll") for (int kb = 0; kb < KB_IN; ++kb) {                               \
      _Pragma("unroll") for (int m = 0; m < 4; ++m) {                                    \
        const int so = (SLOT0 + kb * 4 + m) * 1024 + lane8;                              \
        bf16x8 ah = *(const bf16x8*)&wlds[so];                                           \
        bf16x8 al = *(const bf16x8*)&wlds[so + 512];                                     \
        _Pragma("unroll") for (int p = 0; p < 2; ++p) {                                  \
          sacc[p][m] = __builtin_amdgcn_mfma_f32_16x16x32_bf16(ah, act_h[p][kb], sacc[p][m], 0, 0, 0); \
          sacc[p][m] = __builtin_amdgcn_mfma_f32_16x16x32_bf16(ah, act_l[p][kb], sacc[p][m], 0, 0, 0); \
          sacc[p][m] = __builtin_amdgcn_mfma_f32_16x16x32_bf16(al, act_h[p][kb], sacc[p][m], 0, 0, 0); \
        }                                                                                \
      }                                                                                  \
    }                                                                                    \
    _Pragma("unroll") for (int p = 0; p < 2; ++p) {                                      \
      pack_kb(sacc[p][0], sacc[p][1], &act_h[p][OUTKB], &act_l[p][OUTKB]);               \
      pack_kb(sacc[p][2], sacc[p][3], &act_h[p][OUTKB + 1], &act_l[p][OUTKB + 1]);       \
    }                                                                                    \
  }

__global__ __launch_bounds__(512, 2) void mulut_main(
    const float* __restrict__ x, const float* __restrict__ px_,
    const float* __restrict__ B1, const float* __restrict__ B2,
    const float* __restrict__ B3, const float* __restrict__ B4,
    const float* __restrict__ B5, const float* __restrict__ B6,
    const short* __restrict__ wsw, const float* __restrict__ w1p,
    float* __restrict__ out)
{
    __shared__ short wlds[81920];   // 160 KB

    const int blk = blockIdx.x;             // b*128 + n*16 + q
    const int q   = blk & 15;
    const int n   = (blk >> 4) & 7;
    const int b   = blk >> 7;
    const int c   = (b >= 3) ? 1 : 0;
    const int r   = n >> 1;
    const int batch = n & 1;

    const int tid  = threadIdx.x;
    const int w    = tid >> 6;
    const int lane = tid & 63;
    const int col  = lane & 15;
    const int kq   = lane >> 4;
    const int lane8 = lane << 3;

    const int row   = q * 4 + (w >> 1);
    const int cbase = (w & 1) * 32;

    const char* wsb = (const char*)(wsw + (size_t)b * 92160);

    bf16x8 act_h[2][10];
    bf16x8 act_l[2][10];

    // ================= region A: conv + all scalar global loads =============
    // biases (loaded before staging so their waits never drain staging)
    float bC[16], bS1[16], bS2[16], bS3[16], bS4[16], bH[4];
    #pragma unroll
    for (int i = 0; i < 16; ++i) {
        const int m = i >> 2, rr = i & 3;
        const int ch = m * 16 + kq * 4 + rr;
        bC[i]  = B1[b * 64 + ch];
        bS1[i] = B2[b * 64 + ch];
        bS2[i] = B3[b * 64 + ch];
        bS3[i] = B4[b * 64 + ch];
        bS4[i] = B5[b * 64 + ch];
    }
    #pragma unroll
    for (int rr = 0; rr < 4; ++rr) {
        const int ch = kq * 4 + rr;
        const float t = B6[b * 8 + min(ch, 7)];
        bH[rr] = (ch < 8) ? t : 0.0f;
    }

    // conv taps (rotated + edge-clamped)
    const float* img_[2] = { x   + ((batch * 2 + c) << 12),
                             px_ + ((batch * 2 + c) << 12) };
    float g[2][2][9];
    #pragma unroll
    for (int p = 0; p < 2; ++p) {
        const int c0 = cbase + p * 16 + col;
        #pragma unroll
        for (int di = 0; di < 3; ++di) {
            const int ii = min(row + di, 63);
            #pragma unroll
            for (int dj = 0; dj < 3; ++dj) {
                const int jj = min(c0 + dj, 63);
                int si, sj;
                if      (r == 0) { si = ii;      sj = jj;      }
                else if (r == 1) { si = jj;      sj = 63 - ii; }
                else if (r == 2) { si = 63 - ii; sj = 63 - jj; }
                else             { si = 63 - jj; sj = ii;      }
                g[p][0][di * 3 + dj] = img_[0][si * 64 + sj];
                g[p][1][di * 3 + dj] = img_[1][si * 64 + sj];
            }
        }
    }

    // conv 3x3: 16 ch per thread in permuted-frag order, 2 px
    f32x4 accc[2][4];
    #pragma unroll
    for (int p = 0; p < 2; ++p)
        #pragma unroll
        for (int s16 = 0; s16 < 4; ++s16)
            #pragma unroll
            for (int t = 0; t < 4; ++t)
                accc[p][s16][t] = bC[s16 * 4 + t];

    const f32x4* wp0 = (const f32x4*)&w1p[(b * 4 + kq) * 288];
    #pragma unroll
    for (int it = 0; it < 18; ++it) {       // img*9 + tap
        const int img = it / 9, tap = it % 9;
        const float gv0 = g[0][img][tap];
        const float gv1 = g[1][img][tap];
        #pragma unroll
        for (int s16 = 0; s16 < 4; ++s16) {
            const f32x4 w4 = wp0[it * 4 + s16];
            #pragma unroll
            for (int t = 0; t < 4; ++t) {
                accc[0][s16][t] = fmaf(gv0, w4[t], accc[0][s16][t]);
                accc[1][s16][t] = fmaf(gv1, w4[t], accc[1][s16][t]);
            }
        }
    }
    #pragma unroll
    for (int p = 0; p < 2; ++p) {
        pack_kb(accc[p][0], accc[p][1], &act_h[p][0], &act_l[p][0]);
        pack_kb(accc[p][2], accc[p][3], &act_h[p][1], &act_l[p][1]);
    }

    __builtin_amdgcn_sched_barrier(0);

    // ================= dense weight staging: 20 x 8KB chunks ================
    #pragma unroll
    for (int ck = 0; ck < 20; ++ck) {
        const unsigned off = ck * 8192 + w * 1024;
        __builtin_amdgcn_global_load_lds((const unsigned*)(wsb + off + lane * 16),
                                         (unsigned*)&wlds[off >> 1], 16, 0, 0);
    }
    __builtin_amdgcn_sched_barrier(0);

    // stage 1 needs chunks 0-1 -> 18 newer may remain
    ASM_VMCNT(18);
    __builtin_amdgcn_s_barrier();
    DENSE_STAGE(2, 0, bS1, 2)

    // stage 2 needs chunks 2-5
    ASM_VMCNT(14);
    __builtin_amdgcn_s_barrier();
    DENSE_STAGE(4, 8, bS2, 4)

    // s1/s2 LDS region free -> overlay head weights (20KB @ LDS 0)
    __builtin_amdgcn_s_barrier();
    #pragma unroll
    for (int hk = 0; hk < 2; ++hk) {
        const unsigned loff = hk * 8192 + w * 1024;
        __builtin_amdgcn_global_load_lds((const unsigned*)(wsb + 163840 + loff + lane * 16),
                                         (unsigned*)&wlds[loff >> 1], 16, 0, 0);
    }
    #pragma unroll
    for (int hk = 0; hk < 2; ++hk) {
        const unsigned loff = 16384 + hk * 2048 + w * 256;
        __builtin_amdgcn_global_load_lds((const unsigned*)(wsb + 163840 + loff + lane * 4),
                                         (unsigned*)&wlds[loff >> 1], 4, 0, 0);
    }
    __builtin_amdgcn_sched_barrier(0);

    // stage 3 needs chunks 6-11: newer = 8 dense + 4 head
    ASM_VMCNT(12);
    __builtin_amdgcn_s_barrier();
    DENSE_STAGE(6, 24, bS3, 6)

    // stage 4 needs chunks 12-19: newer = 4 head
    ASM_VMCNT(4);
    __builtin_amdgcn_s_barrier();
    DENSE_STAGE(8, 48, bS4, 8)

    // head needs its 4 chunks
    ASM_VMCNT(0);
    __builtin_amdgcn_s_barrier();

    // ================= head (M=16 padded, K=320) ============================
    f32x4 hacc[2];
    #pragma unroll
    for (int p = 0; p < 2; ++p)
        #pragma unroll
        for (int rr = 0; rr < 4; ++rr)
            hacc[p][rr] = bH[rr];
    #pragma unroll
    for (int kb = 0; kb < 10; ++kb) {
        const int so = kb * 1024 + lane8;
        bf16x8 ah = *(const bf16x8*)&wlds[so];
        bf16x8 al = *(const bf16x8*)&wlds[so + 512];
        #pragma unroll
        for (int p = 0; p < 2; ++p) {
            hacc[p] = __builtin_amdgcn_mfma_f32_16x16x32_bf16(ah, act_h[p][kb], hacc[p], 0, 0, 0);
            hacc[p] = __builtin_amdgcn_mfma_f32_16x16x32_bf16(ah, act_l[p][kb], hacc[p], 0, 0, 0);
            hacc[p] = __builtin_amdgcn_mfma_f32_16x16x32_bf16(al, act_h[p][kb], hacc[p], 0, 0, 0);
        }
    }

    // ================= epilogue: shuffle + inv-rot + round(tanh*127) ========
    #pragma unroll
    for (int p = 0; p < 2; ++p) {
        const int colp = cbase + p * 16 + col;
        #pragma unroll
        for (int rr = 0; rr < 4; ++rr) {
            const int ch = kq * 4 + rr;
            if (ch < 8) {
                const int oc = ch >> 2;
                const int a  = (ch >> 1) & 1;
                const int bb = ch & 1;
                const int ip = 2 * row + a;
                const int jp = 2 * colp + bb;
                int I, J;
                if      (r == 0) { I = ip;       J = jp;       }
                else if (r == 1) { I = jp;       J = 127 - ip; }
                else if (r == 2) { I = 127 - ip; J = 127 - jp; }
                else             { I = 127 - jp; J = ip;       }
                const float v = rintf(tanhf(hacc[p][rr]) * 127.0f);
                atomicAdd(out + (((batch * 2 + oc) << 14) + I * 128 + J), v * 0.5f);
            }
        }
    }
}

extern "C" void kernel_launch(void* const* d_in, const int* in_sizes, int n_in,
                              void* d_out, int out_size, void* d_ws, size_t ws_size,
                              hipStream_t stream) {
    const float* x   = (const float*)d_in[0];
    const float* pxv = (const float*)d_in[1];
    const float* W1  = (const float*)d_in[2];
    const float* B1  = (const float*)d_in[3];
    const float* W2  = (const float*)d_in[4];
    const float* B2  = (const float*)d_in[5];
    const float* W3  = (const float*)d_in[6];
    const float* B3  = (const float*)d_in[7];
    const float* W4  = (const float*)d_in[8];
    const float* B4  = (const float*)d_in[9];
    const float* W5  = (const float*)d_in[10];
    const float* B5  = (const float*)d_in[11];
    const float* W6  = (const float*)d_in[12];
    const float* B6  = (const float*)d_in[13];
    float* out = (float*)d_out;

    short* wsw = (short*)d_ws;                       // 6 * 92160 shorts
    float* w1p = (float*)(wsw + 6 * 92160);          // 6912 floats

    hipMemsetAsync(out, 0, (size_t)out_size * sizeof(float), stream);
    prep_weights<<<dim3(136), dim3(256), 0, stream>>>(W1, W2, W3, W4, W5, W6, wsw, w1p);
    mulut_main<<<dim3(768), dim3(512), 0, stream>>>(
        x, pxv, B1, B2, B3, B4, B5, B6, wsw, w1p, out);
}